// Round 8
// baseline (245.825 us; speedup 1.0000x reference)
//
#include <hip/hip_runtime.h>
#include <hip/hip_bf16.h>

typedef unsigned short ushort_t;
typedef __attribute__((ext_vector_type(4))) float v4f;
typedef __attribute__((ext_vector_type(8))) short v8s;

#define FDIM 128
#define KCLUST 16
#define CSTRIDE 264   // combined-row stride in bf16 elems
#define QSTRIDE 24    // q row stride in shorts (48B)
#define SS 10         // compile-time S fast path

__device__ __forceinline__ ushort_t f2bf(float x) {
    unsigned int u = __float_as_uint(x);
    unsigned int r = (u + 0x7fffu + ((u >> 16) & 1u)) >> 16;
    return (ushort_t)r;
}
__device__ __forceinline__ float bf2f(ushort_t h) {
    return __uint_as_float((unsigned int)h << 16);
}
__device__ __forceinline__ float wave_reduce_sum(float v) {
    #pragma unroll
    for (int off = 32; off > 0; off >>= 1) v += __shfl_xor(v, off, 64);
    return v;
}

union V8U { v8s v; ushort_t u[8]; };

// ---------------------------------------------------------------------------
// Kernel 1: cast weight (E x 256 f32) -> bf16, padded to Np rows (zeros).
// ---------------------------------------------------------------------------
__global__ void pack_weight(const float* __restrict__ W, ushort_t* __restrict__ Wb,
                            long total, long valid) {
    long i = ((long)blockIdx.x * blockDim.x + threadIdx.x) * 4;
    if (i >= total) return;
    float4 v;
    if (i < valid) v = *(const float4*)(W + i);
    else           v = make_float4(0.f, 0.f, 0.f, 0.f);
    ushort_t* dst = Wb + i;
    dst[0] = f2bf(v.x); dst[1] = f2bf(v.y); dst[2] = f2bf(v.z); dst[3] = f2bf(v.w);
}

// ---------------------------------------------------------------------------
// Kernel 2 (fused), v9: DE-SERIALIZED S. v4/v6/v8 all plateau at 60-68us
//   with nothing saturated: the serial S-loop (10 x {gather chain ->
//   butterflies -> barrier -> wave0 cross/q -> barrier -> m}) is ~2-3K cycles
//   of latency per iteration that occupancy never hid. att/q/m are
//   independent per s; only the final sum over s is a reduction. v9 runs
//   phase A as 3 bulk stages over all 160 (row,s) pairs (16-row block):
//     G: 10 independent gather rounds (loads bulk-issued), bf16 N -> LDS,
//        logit/n2 butterflies per round (ILP across rounds)    [barrier]
//     X: cross[160,16] = N @ center^T as 10 MFMA tiles over 8 waves; q
//        split-bf16 -> LDS                                      [barrier]
//     M: per wave (16-feat column): 10 tiles x 3 MFMA m-GEMM fused with
//        att*n*m accumulate; n re-read from global (LLC-hot; kills the
//        80KB f32 LDS copy). 3 barriers/block total instead of 20.
//   Pair p = s*16+row so pair-tile s holds all 16 rows of neighbor s.
// ---------------------------------------------------------------------------
__global__ __launch_bounds__(512, 2) void fused_agg_s10(
    const int* __restrict__ nodes, const int* __restrict__ neigh_idx,
    const float* __restrict__ self_table, const float* __restrict__ neigh_table,
    const float* __restrict__ center, const float* __restrict__ cluster_mask,
    const float* __restrict__ alpha, const ushort_t* __restrict__ Wb,
    float* __restrict__ out, int B, int E) {

    __shared__ __align__(16) ushort_t comb[16 * CSTRIDE];      // 8448 B
    __shared__ __align__(16) ushort_t nbf[SS * 16 * 128];      // 40960 B
    __shared__ __align__(16) ushort_t qhi[SS * 16 * QSTRIDE];  // 7680 B
    __shared__ __align__(16) ushort_t qlo[SS * 16 * QSTRIDE];  // 7680 B
    __shared__ __align__(16) float    attL[SS * 16];           // 640 B
    __shared__ __align__(16) float    n2L[SS * 16];            // 640 B
    __shared__ __align__(16) int      idxL[SS * 16];           // 640 B

    const int t    = threadIdx.x;
    const int lane = t & 63, wave = t >> 6;   // 8 waves
    const int g    = t >> 5;                  // row 0..15 (gather group)
    const int fq   = t & 31;                  // feat-quad within group
    const int f0   = fq << 2;
    const int l16  = lane & 15, quad = lane >> 4;

    const int b0 = blockIdx.x * 16;
    int bg = b0 + g; if (bg >= B) bg = B - 1;  // clamp loads; stores guarded

    const float4 aS = *(const float4*)(alpha + f0);
    const float4 aN = *(const float4*)(alpha + FDIM + f0);

    // ---- self features: stage to comb (bf16) + logit_self butterfly ----
    float ls;
    {
        size_t node = (size_t)nodes[bg];
        float4 sf = *(const float4*)(self_table + node * FDIM + f0);
        ushort_t h0 = f2bf(sf.x), h1 = f2bf(sf.y), h2 = f2bf(sf.z), h3 = f2bf(sf.w);
        uint2 pk;
        pk.x = (unsigned)h0 | ((unsigned)h1 << 16);
        pk.y = (unsigned)h2 | ((unsigned)h3 << 16);
        *(uint2*)(comb + g * CSTRIDE + f0) = pk;
        ls = sf.x * aS.x + sf.y * aS.y + sf.z * aS.z + sf.w * aS.w;
        #pragma unroll
        for (int off = 1; off <= 16; off <<= 1) ls += __shfl_xor(ls, off, 64);
    }

    // ---- ALL waves: center B-fragments (bf16) + c2 (exact f32) ----
    v8s cbf[4]; float c2v = 0.f;
    {
        const float* crow = center + l16 * FDIM;
        #pragma unroll
        for (int kk = 0; kk < 4; kk++) {
            const float* p = crow + kk * 32 + quad * 8;
            float4 x = *(const float4*)p;
            float4 y = *(const float4*)(p + 4);
            V8U pk;
            pk.u[0] = f2bf(x.x); pk.u[1] = f2bf(x.y); pk.u[2] = f2bf(x.z); pk.u[3] = f2bf(x.w);
            pk.u[4] = f2bf(y.x); pk.u[5] = f2bf(y.y); pk.u[6] = f2bf(y.z); pk.u[7] = f2bf(y.w);
            cbf[kk] = pk.v;
            c2v += x.x*x.x + x.y*x.y + x.z*x.z + x.w*x.w
                 + y.x*y.x + y.y*y.y + y.z*y.z + y.w*y.w;
        }
        c2v += __shfl_xor(c2v, 16, 64);
        c2v += __shfl_xor(c2v, 32, 64);
    }

    // ---- mask B-fragments for this wave's 16-feature column (split bf16) ----
    v8s mhi, mlo;
    {
        V8U ph, pl;
        const int fc = wave * 16 + l16;
        #pragma unroll
        for (int j = 0; j < 8; j++) {
            float mv = (quad < 2) ? cluster_mask[(quad * 8 + j) * FDIM + fc] : 0.f;
            ushort_t h = f2bf(mv);
            ph.u[j] = h; pl.u[j] = f2bf(mv - bf2f(h));
        }
        mhi = ph.v; mlo = pl.v;
    }

    // ================= stage G: bulk gather =================
    int idxv[SS];
    #pragma unroll
    for (int j = 0; j < SS; j++) idxv[j] = neigh_idx[(size_t)bg * SS + j];
    if (fq == 0) {
        #pragma unroll
        for (int j = 0; j < SS; j++) idxL[j * 16 + g] = idxv[j];
    }

    #pragma unroll
    for (int j = 0; j < SS; j++) {
        const float4 cur = *(const float4*)(neigh_table + (size_t)idxv[j] * FDIM + f0);
        // stage bf16 N, XOR-swizzled 16B slots (row = pair & 15 = g)
        {
            ushort_t h0 = f2bf(cur.x), h1 = f2bf(cur.y), h2 = f2bf(cur.z), h3 = f2bf(cur.w);
            uint2 pk;
            pk.x = (unsigned)h0 | ((unsigned)h1 << 16);
            pk.y = (unsigned)h2 | ((unsigned)h3 << 16);
            const int slot = (fq >> 1) ^ g;
            *(uint2*)((char*)nbf + (j * 16 + g) * 256 + slot * 16 + (fq & 1) * 8) = pk;
        }
        float pn = cur.x * aN.x + cur.y * aN.y + cur.z * aN.z + cur.w * aN.w;
        float p2 = cur.x * cur.x + cur.y * cur.y + cur.z * cur.z + cur.w * cur.w;
        #pragma unroll
        for (int off = 1; off <= 16; off <<= 1) {
            pn += __shfl_xor(pn, off, 64);
            p2 += __shfl_xor(p2, off, 64);
        }
        const float att = __expf(fmaxf(ls + pn, 0.f));
        if (fq == 0) { attL[j * 16 + g] = att; n2L[j * 16 + g] = p2; }
    }

    // ---- barrier 1 (lgkm only) ----
    asm volatile("s_waitcnt lgkmcnt(0)" ::: "memory");
    __builtin_amdgcn_s_barrier();
    asm volatile("" ::: "memory");

    // ---- preload n for stage M (global, LLC-hot; latency hides under X) ----
    const int fcol = wave * 16 + l16;
    float nReg[SS * 4];
    #pragma unroll
    for (int s = 0; s < SS; s++) {
        const int4 iv = *(const int4*)&idxL[s * 16 + quad * 4];
        nReg[s * 4 + 0] = neigh_table[(size_t)iv.x * FDIM + fcol];
        nReg[s * 4 + 1] = neigh_table[(size_t)iv.y * FDIM + fcol];
        nReg[s * 4 + 2] = neigh_table[(size_t)iv.z * FDIM + fcol];
        nReg[s * 4 + 3] = neigh_table[(size_t)iv.w * FDIM + fcol];
    }

    // ================= stage X: cross + q (tiles s = wave, wave+8) =========
    for (int s = wave; s < SS; s += 8) {
        v4f xacc = {0.f, 0.f, 0.f, 0.f};
        #pragma unroll
        for (int kk = 0; kk < 4; kk++) {
            const int sl = (kk * 4 + quad) ^ l16;
            v8s af = *(const v8s*)((const char*)nbf + (s * 16 + l16) * 256 + sl * 16);
            xacc = __builtin_amdgcn_mfma_f32_16x16x32_bf16(af, cbf[kk], xacc, 0, 0, 0);
        }
        const float4 n2r = *(const float4*)&n2L[s * 16 + quad * 4];
        #pragma unroll
        for (int r = 0; r < 4; r++) {
            const float n2v = (r == 0) ? n2r.x : (r == 1) ? n2r.y : (r == 2) ? n2r.z : n2r.w;
            const float d  = n2v - 2.f * xacc[r] + c2v;
            const float qv = 1.f / (d + 1.f);
            const ushort_t h = f2bf(qv);
            qhi[(s * 16 + quad * 4 + r) * QSTRIDE + l16] = h;
            qlo[(s * 16 + quad * 4 + r) * QSTRIDE + l16] = f2bf(qv - bf2f(h));
        }
    }

    // ---- barrier 2 (lgkm only; nReg loads stay in flight) ----
    asm volatile("s_waitcnt lgkmcnt(0)" ::: "memory");
    __builtin_amdgcn_s_barrier();
    asm volatile("" ::: "memory");

    // ================= stage M: m-GEMM + weighted reduce over s =============
    float a0 = 0.f, a1 = 0.f, a2 = 0.f, a3 = 0.f;
    float t0 = 0.f, t1 = 0.f, t2 = 0.f, t3 = 0.f;   // attsum per row
    #pragma unroll
    for (int s = 0; s < SS; s++) {
        // A-frag: lane l16 = pair-local row; quads 2,3 mirror (B rows k>=16 = 0)
        v8s aqh = *(const v8s*)(qhi + (s * 16 + l16) * QSTRIDE + (quad & 1) * 8);
        v8s aql = *(const v8s*)(qlo + (s * 16 + l16) * QSTRIDE + (quad & 1) * 8);
        v4f mac = {0.f, 0.f, 0.f, 0.f};
        mac = __builtin_amdgcn_mfma_f32_16x16x32_bf16(aqh, mhi, mac, 0, 0, 0);
        mac = __builtin_amdgcn_mfma_f32_16x16x32_bf16(aql, mhi, mac, 0, 0, 0);
        mac = __builtin_amdgcn_mfma_f32_16x16x32_bf16(aqh, mlo, mac, 0, 0, 0);
        const float4 attq = *(const float4*)&attL[s * 16 + quad * 4];
        a0 = fmaf(attq.x * mac[0], nReg[s * 4 + 0], a0); t0 += attq.x;
        a1 = fmaf(attq.y * mac[1], nReg[s * 4 + 1], a1); t1 += attq.y;
        a2 = fmaf(attq.z * mac[2], nReg[s * 4 + 2], a2); t2 += attq.z;
        a3 = fmaf(attq.w * mac[3], nReg[s * 4 + 3], a3); t3 += attq.w;
    }
    {
        ushort_t* cp = comb + 128 + fcol;
        cp[(quad * 4 + 0) * CSTRIDE] = f2bf(a0 / t0);
        cp[(quad * 4 + 1) * CSTRIDE] = f2bf(a1 / t1);
        cp[(quad * 4 + 2) * CSTRIDE] = f2bf(a2 / t2);
        cp[(quad * 4 + 3) * CSTRIDE] = f2bf(a3 / t3);
    }

    // ---------------- phase B: out[16][E] = relu(comb @ Wb^T) ---------------
    const int Ntiles = (E + 15) >> 4;

    v8s bfr[8];
    {
        const int nt0 = (wave < Ntiles) ? wave : 0;
        const ushort_t* wrow = Wb + (size_t)(nt0 * 16 + l16) * 256 + quad * 8;
        #pragma unroll
        for (int kk = 0; kk < 8; kk++)
            bfr[kk] = *(const v8s*)(wrow + kk * 32);
    }

    // ---- barrier 3 (lgkm only; W prefetch stays in flight) ----
    asm volatile("s_waitcnt lgkmcnt(0)" ::: "memory");
    __builtin_amdgcn_s_barrier();
    asm volatile("" ::: "memory");

    v8s afr[8];
    #pragma unroll
    for (int kk = 0; kk < 8; kk++)
        afr[kk] = *(const v8s*)(comb + l16 * CSTRIDE + kk * 32 + quad * 8);

    for (int nt = wave; nt < Ntiles; nt += 8) {
        if (nt != wave) {
            const ushort_t* wrow = Wb + (size_t)(nt * 16 + l16) * 256 + quad * 8;
            #pragma unroll
            for (int kk = 0; kk < 8; kk++)
                bfr[kk] = *(const v8s*)(wrow + kk * 32);
        }
        v4f acc = {0.f, 0.f, 0.f, 0.f};
        #pragma unroll
        for (int kk = 0; kk < 8; kk++)
            acc = __builtin_amdgcn_mfma_f32_16x16x32_bf16(afr[kk], bfr[kk], acc, 0, 0, 0);
        const int gcol = nt * 16 + l16;
        if (gcol < E) {
            #pragma unroll
            for (int rr = 0; rr < 4; rr++) {
                const int grow = b0 + quad * 4 + rr;
                if (grow < B)
                    out[(size_t)grow * E + gcol] = fmaxf(acc[rr], 0.f);
            }
        }
    }
}

// ---------------------------------------------------------------------------
// Generic fallback (any S), exact f32, 1 wave per output row. Never used for
// the benched shape (S=10); kept for correctness on other shapes.
// ---------------------------------------------------------------------------
__global__ void fused_generic(
    const int* __restrict__ nodes, const int* __restrict__ neigh_idx,
    const float* __restrict__ self_table, const float* __restrict__ neigh_table,
    const float* __restrict__ center, const float* __restrict__ cluster_mask,
    const float* __restrict__ alpha, const float* __restrict__ weight,
    float* __restrict__ out, int B, int S, int E) {

    __shared__ float combsh[256];
    const int b = blockIdx.x;
    const int lane = threadIdx.x;  // 64 threads

    float s0 = self_table[(size_t)nodes[b] * FDIM + lane];
    float s1 = self_table[(size_t)nodes[b] * FDIM + 64 + lane];
    const float ls = wave_reduce_sum(s0 * alpha[lane] + s1 * alpha[64 + lane]);

    float acc0 = 0.f, acc1 = 0.f, attsum = 0.f;
    for (int s = 0; s < S; s++) {
        const size_t idx = (size_t)neigh_idx[(size_t)b * S + s];
        const float n0 = neigh_table[idx * FDIM + lane];
        const float n1 = neigh_table[idx * FDIM + 64 + lane];
        const float ln = wave_reduce_sum(n0 * alpha[128 + lane] + n1 * alpha[192 + lane]);
        const float att = __expf(fmaxf(ls + ln, 0.f));
        float m0 = 0.f, m1 = 0.f;
        for (int k = 0; k < KCLUST; k++) {
            const float c0 = center[k * FDIM + lane];
            const float c1 = center[k * FDIM + 64 + lane];
            const float d = wave_reduce_sum((n0 - c0) * (n0 - c0) + (n1 - c1) * (n1 - c1));
            const float qv = 1.f / (d + 1.f);
            m0 += qv * cluster_mask[k * FDIM + lane];
            m1 += qv * cluster_mask[k * FDIM + 64 + lane];
        }
        acc0 += att * n0 * m0; acc1 += att * n1 * m1; attsum += att;
    }
    const float inv = 1.f / attsum;
    combsh[lane] = s0; combsh[64 + lane] = s1;
    combsh[128 + lane] = acc0 * inv; combsh[192 + lane] = acc1 * inv;
    __syncthreads();
    for (int e = lane; e < E; e += 64) {
        const float* wr = weight + (size_t)e * 256;
        float o = 0.f;
        for (int j = 0; j < 256; j++) o += combsh[j] * wr[j];
        out[(size_t)b * E + e] = fmaxf(o, 0.f);
    }
}

extern "C" void kernel_launch(void* const* d_in, const int* in_sizes, int n_in,
                              void* d_out, int out_size, void* d_ws, size_t ws_size,
                              hipStream_t stream) {
    const int*   nodes        = (const int*)d_in[0];
    const int*   neigh_idx    = (const int*)d_in[1];
    const float* self_table   = (const float*)d_in[2];
    const float* neigh_table  = (const float*)d_in[3];
    const float* center       = (const float*)d_in[4];
    const float* cluster_mask = (const float*)d_in[5];
    const float* weight       = (const float*)d_in[6];
    const float* alpha        = (const float*)d_in[7];
    float* out = (float*)d_out;

    int B = in_sizes[0];
    int S = in_sizes[1] / B;
    int E = in_sizes[6] / (2 * FDIM);

    if (S == SS) {
        int Np = ((E + 15) / 16) * 16;
        ushort_t* Wb = (ushort_t*)d_ws;   // Np x 256 bf16
        long totalW = (long)Np * 256;
        long validW = (long)E * 256;
        int blksW = (int)((totalW + 1023) / 1024);
        pack_weight<<<blksW, 256, 0, stream>>>(weight, Wb, totalW, validW);

        int nblk = (B + 15) / 16;
        fused_agg_s10<<<nblk, 512, 0, stream>>>(
            nodes, neigh_idx, self_table, neigh_table, center, cluster_mask,
            alpha, Wb, out, B, E);
    } else {
        fused_generic<<<B, 64, 0, stream>>>(
            nodes, neigh_idx, self_table, neigh_table, center, cluster_mask,
            alpha, weight, out, B, S, E);
    }
}